// Round 10
// baseline (766.114 us; speedup 1.0000x reference)
//
#include <hip/hip_runtime.h>
#include <hip/hip_bf16.h>

#define HID 16
#define NFEAT 512
#define BW 64           // nodes per bucket (dst >> 6)
#define CH 16384        // edges per histogram/scatter block
#define MAXB 2048       // max buckets supported by bucket path

typedef __attribute__((ext_vector_type(8))) short bf16x8;
typedef __attribute__((ext_vector_type(4))) float f32x4;

__device__ __forceinline__ unsigned short f2b_hw(float f) {
    __hip_bfloat16 h = __float2bfloat16(f);
    return *reinterpret_cast<unsigned short*>(&h);
}
__device__ __forceinline__ float b2f(unsigned short b) {
    return __uint_as_float(((unsigned)b) << 16);
}

// ================= bucket build =================
__global__ __launch_bounds__(1024) void khist(const int* __restrict__ dst,
                                              int* __restrict__ gcount, int e, int nbkt) {
    __shared__ int hist[MAXB];
    for (int t = threadIdx.x; t < nbkt; t += 1024) hist[t] = 0;
    __syncthreads();
    int base = blockIdx.x * CH;
#pragma unroll
    for (int k = 0; k < CH / 1024; ++k) {
        int i = base + k * 1024 + threadIdx.x;
        if (i < e) atomicAdd(&hist[dst[i] >> 6], 1);
    }
    __syncthreads();
    for (int t = threadIdx.x; t < nbkt; t += 1024)
        if (hist[t]) atomicAdd(&gcount[t], hist[t]);
}

__global__ __launch_bounds__(1024) void kscan(const int* __restrict__ gcount,
                                              int* __restrict__ goff,
                                              int* __restrict__ gcursor, int nbkt) {
    __shared__ int buf0[MAXB], buf1[MAXB];
    for (int t = threadIdx.x; t < MAXB; t += 1024) buf0[t] = (t < nbkt) ? gcount[t] : 0;
    __syncthreads();
    int* in = buf0; int* out = buf1;
    for (int d = 1; d < MAXB; d <<= 1) {
        for (int t = threadIdx.x; t < MAXB; t += 1024)
            out[t] = in[t] + (t >= d ? in[t - d] : 0);
        __syncthreads();
        int* tmp = in; in = out; out = tmp;
    }
    for (int t = threadIdx.x; t < nbkt; t += 1024) {
        int excl = in[t] - gcount[t];
        goff[t] = excl;
        gcursor[t] = excl;
    }
    if (threadIdx.x == 0) goff[nbkt] = in[nbkt - 1];
}

// LDS-presorted scatter of PACKED edges: pk = (src<<6) | (dst & 63).
__global__ __launch_bounds__(1024) void kscatter(const int* __restrict__ src,
                                                 const int* __restrict__ dst,
                                                 int* __restrict__ gcursor,
                                                 unsigned* __restrict__ pk, int e, int nbkt) {
    __shared__ int hist[MAXB];
    __shared__ int base[MAXB];
    for (int t = threadIdx.x; t < nbkt; t += 1024) hist[t] = 0;
    __syncthreads();
    int b0 = blockIdx.x * CH;
#pragma unroll
    for (int k = 0; k < CH / 1024; ++k) {
        int i = b0 + k * 1024 + threadIdx.x;
        if (i < e) atomicAdd(&hist[dst[i] >> 6], 1);
    }
    __syncthreads();
    for (int t = threadIdx.x; t < nbkt; t += 1024)
        base[t] = hist[t] ? atomicAdd(&gcursor[t], hist[t]) : 0;
    __syncthreads();
#pragma unroll
    for (int k = 0; k < CH / 1024; ++k) {
        int i = b0 + k * 1024 + threadIdx.x;
        if (i < e) {
            int d = dst[i];
            int pos = atomicAdd(&base[d >> 6], 1);   // LDS bump
            pk[pos] = ((unsigned)src[i] << 6) | (unsigned)(d & 63);
        }
    }
}

// ================= per-bucket degree =================
__global__ __launch_bounds__(256) void kdeg(const unsigned* __restrict__ pk,
                                            const int* __restrict__ goff,
                                            float* __restrict__ dis, int n) {
    __shared__ int cnt[BW];
    int b = blockIdx.x;
    if (threadIdx.x < BW) cnt[threadIdx.x] = 0;
    __syncthreads();
    int s0 = goff[b], s1 = goff[b + 1];
    for (int i = s0 + threadIdx.x; i < s1; i += 256)
        atomicAdd(&cnt[pk[i] & 63], 1);
    __syncthreads();
    if (threadIdx.x < BW) {
        int node = b * BW + threadIdx.x;
        if (node < n) dis[node] = rsqrtf(1.0f + (float)cnt[threadIdx.x]);
    }
}

// ================= W1 -> Wt (bf16 transposed) =================
__global__ __launch_bounds__(256) void prep_wt(const float* __restrict__ W1,
                                               unsigned short* __restrict__ Wt) {
    int i = blockIdx.x * 256 + threadIdx.x;   // 8192 = 16*512
    int j = i >> 9, k = i & 511;
    Wt[i] = f2b_hw(W1[k * HID + j]);
}

// ================= h1 = x @ W1 via MFMA (proven) =================
__global__ __launch_bounds__(256) void mm1_mfma(const float* __restrict__ x,
                                                const unsigned short* __restrict__ Wt,
                                                const float* __restrict__ dis,
                                                float* __restrict__ h1,
                                                unsigned short* __restrict__ hsb, int n) {
    int wid  = threadIdx.x >> 6;
    int lane = threadIdx.x & 63;
    int base = (blockIdx.x * 4 + wid) * 16;
    if (base >= n) return;
    int lrow = lane & 15;
    int kg   = lane >> 4;

    bf16x8 bfr[16];
#pragma unroll
    for (int t = 0; t < 16; ++t)
        bfr[t] = *(const bf16x8*)(Wt + lrow * NFEAT + t * 32 + kg * 8);

    int row = base + lrow;
    bool ok = (row < n);
    const float* xr = x + (size_t)(ok ? row : 0) * NFEAT;

    f32x4 acc = {0.f, 0.f, 0.f, 0.f};
#pragma unroll
    for (int t = 0; t < 16; ++t) {
        float4 u0 = *(const float4*)(xr + t * 32 + kg * 8);
        float4 u1 = *(const float4*)(xr + t * 32 + kg * 8 + 4);
        if (!ok) { u0 = make_float4(0,0,0,0); u1 = make_float4(0,0,0,0); }
        union { bf16x8 v; unsigned short u[8]; } A;
        A.u[0] = f2b_hw(u0.x); A.u[1] = f2b_hw(u0.y);
        A.u[2] = f2b_hw(u0.z); A.u[3] = f2b_hw(u0.w);
        A.u[4] = f2b_hw(u1.x); A.u[5] = f2b_hw(u1.y);
        A.u[6] = f2b_hw(u1.z); A.u[7] = f2b_hw(u1.w);
        acc = __builtin_amdgcn_mfma_f32_16x16x32_bf16(A.v, bfr[t], acc, 0, 0, 0);
    }

#pragma unroll
    for (int q = 0; q < 4; ++q) {
        int orow = base + kg * 4 + q;
        if (orow < n) {
            float v = acc[q];
            h1[(size_t)orow * HID + lrow] = v;
            hsb[(size_t)orow * HID + lrow] = f2b_hw(v * dis[orow]);
        }
    }
}

// ================= per-bucket aggregation, forced-MLP version =================
// Round-9 failure: compiler re-interleaved the unrolled loop (VGPR_Count=12 ->
// ~1 gather in flight). Fix: branch-free load phase into val[16]/dloc[16]
// register arrays, then sched_barrier(0) (scheduler may not move memory ops
// across), then the 16 LDS atomics. Forces 16 gathers in flight per group.
__global__ __launch_bounds__(256) void kagg(const unsigned* __restrict__ pk,
                                            const int* __restrict__ goff,
                                            const unsigned short* __restrict__ hsb,
                                            float* __restrict__ out, int n) {
    __shared__ float acc[BW * 17];
    __shared__ unsigned stage[256];
    int b = blockIdx.x;
    for (int t = threadIdx.x; t < BW * 17; t += 256) acc[t] = 0.f;
    int s0 = goff[b], s1 = goff[b + 1];
    int g = threadIdx.x >> 4, j = threadIdx.x & 15;
    __syncthreads();

    int base = s0;
    // main loop: full 256-edge chunks, branch-free
    for (; base + 256 <= s1; base += 256) {
        stage[threadIdx.x] = pk[base + threadIdx.x];
        __syncthreads();
        float    val[16];
        unsigned dloc[16];
#pragma unroll
        for (int u = 0; u < 16; ++u) {
            unsigned v = stage[u * 16 + g];
            dloc[u] = (v & 63u) * 17 + j;
            val[u]  = b2f(hsb[(size_t)(v >> 6) * HID + j]);
        }
        __builtin_amdgcn_sched_barrier(0);   // all 16 gathers issued before atomics
#pragma unroll
        for (int u = 0; u < 16; ++u)
            atomicAdd(&acc[dloc[u]], val[u]);
        __syncthreads();
    }
    // tail chunk (guarded)
    if (base < s1) {
        int i = base + threadIdx.x;
        if (i < s1) stage[threadIdx.x] = pk[i];
        int cnt = s1 - base;
        __syncthreads();
#pragma unroll
        for (int u = 0; u < 16; ++u) {
            int r = u * 16 + g;
            if (r < cnt) {
                unsigned v = stage[r];
                atomicAdd(&acc[(v & 63u) * 17 + j], b2f(hsb[(size_t)(v >> 6) * HID + j]));
            }
        }
        __syncthreads();
    }

#pragma unroll
    for (int r0 = 0; r0 < BW; r0 += 16) {
        int r = r0 + g;
        int node = b * BW + r;
        if (node < n) out[(size_t)node * HID + j] = acc[r * 17 + j];
    }
}

// ================= fused middle / final =================
__global__ __launch_bounds__(256) void mid(const float* __restrict__ agg1,
                                           float* __restrict__ h1,
                                           unsigned short* __restrict__ hsb,
                                           const float* __restrict__ dis,
                                           const float* __restrict__ b1,
                                           const float* __restrict__ W2, int n) {
    __shared__ float W2s[HID * HID];
    W2s[threadIdx.x] = W2[threadIdx.x];
    __syncthreads();
    int idx = blockIdx.x * 256 + threadIdx.x;
    int v = idx >> 4, j = idx & 15;
    if (v >= n) return;
    float dn = dis[v];
    float a = dn * agg1[idx] + dn * dn * h1[idx] + b1[j];
    float hv = fmaxf(a, 0.f);
    float h2 = 0.f;
#pragma unroll
    for (int k = 0; k < HID; ++k)
        h2 += __shfl(hv, k, HID) * W2s[k * HID + j];
    h1[idx] = h2;
    hsb[idx] = f2b_hw(h2 * dn);
}

__global__ __launch_bounds__(256) void finalk(float* __restrict__ out,
                                              const float* __restrict__ h2,
                                              const float* __restrict__ dis,
                                              const float* __restrict__ b2,
                                              const float* __restrict__ eps, int n) {
    int idx = blockIdx.x * 256 + threadIdx.x;
    int v = idx >> 4, j = idx & 15;
    if (v >= n) return;
    float dn = dis[v];
    float z = dn * out[idx] + dn * dn * h2[idx] + b2[j];
    out[idx] = z + eps[idx] * expf(0.5f * z);
}

// ================= fallback (round-7 atomic path) =================
__global__ __launch_bounds__(256) void deg_count_int(const int* __restrict__ dst,
                                                     int* __restrict__ ideg, int e) {
    int i = blockIdx.x * 256 + threadIdx.x;
    if (i < e) atomicAdd(&ideg[dst[i]], 1);
}
__global__ __launch_bounds__(256) void make_dis(const int* __restrict__ ideg,
                                                float* __restrict__ dis, int n) {
    int i = blockIdx.x * 256 + threadIdx.x;
    if (i < n) dis[i] = rsqrtf(1.0f + (float)ideg[i]);
}
__global__ __launch_bounds__(256) void prop(const int* __restrict__ src,
                                            const int* __restrict__ dst,
                                            const unsigned short* __restrict__ hsb,
                                            float* __restrict__ agg, int e) {
    int idx = blockIdx.x * 256 + threadIdx.x;
    int ed = idx >> 4, j = idx & 15;
    if (ed >= e) return;
    int s = src[ed], d = dst[ed];
    atomicAdd(&agg[(size_t)d * HID + j], b2f(hsb[(size_t)s * HID + j]));
}

extern "C" void kernel_launch(void* const* d_in, const int* in_sizes, int n_in,
                              void* d_out, int out_size, void* d_ws, size_t ws_size,
                              hipStream_t stream) {
    const float* x   = (const float*)d_in[0];
    const float* W1  = (const float*)d_in[1];
    const float* b1  = (const float*)d_in[2];
    const float* W2  = (const float*)d_in[3];
    const float* b2  = (const float*)d_in[4];
    const float* eps = (const float*)d_in[5];
    const int*   ei  = (const int*)d_in[6];

    int n = in_sizes[5] / HID;   // 100000
    int e = in_sizes[6] / 2;     // 3200000
    const int* srcs = ei;
    const int* dsts = ei + e;
    float* outf = (float*)d_out;

    int nbkt    = (n + BW - 1) / BW;         // 1563
    int nBlk    = (n + 255) / 256;
    int eBlk    = (e + 255) / 256;
    int mmBlk   = (n + 63) / 64;
    int featBlk = (n * 16 + 255) / 256;
    int chBlk   = (e + CH - 1) / CH;         // 196

    // bucket-path ws: [pk 4e][gcount][goff][gcursor][dis 4n][h1 64n][agg1 64n][hsb 32n][Wt 16K]
    size_t needBucket = (size_t)e * 4 + 3 * (size_t)(MAXB + 2) * 4
                      + (size_t)n * 4 + (size_t)n * 64 * 2 + (size_t)n * 32 + 16384;
    bool bucketPath = (nbkt <= MAXB) && ((size_t)n < (1u << 26)) && (ws_size >= needBucket);

    if (bucketPath) {
        unsigned*       pk      = (unsigned*)d_ws;
        int*            gcount  = (int*)(pk + e);
        int*            goff    = gcount + (MAXB + 2);
        int*            gcursor = goff + (MAXB + 2);
        float*          dis     = (float*)(gcursor + (MAXB + 2));
        float*          h1      = dis + n;
        float*          agg1    = h1 + (size_t)n * HID;
        unsigned short* hsb     = (unsigned short*)(agg1 + (size_t)n * HID);
        unsigned short* Wt      = hsb + (size_t)n * HID;

        hipMemsetAsync(gcount, 0, (size_t)(MAXB + 2) * 4, stream);
        khist<<<chBlk, 1024, 0, stream>>>(dsts, gcount, e, nbkt);
        kscan<<<1, 1024, 0, stream>>>(gcount, goff, gcursor, nbkt);
        kscatter<<<chBlk, 1024, 0, stream>>>(srcs, dsts, gcursor, pk, e, nbkt);
        kdeg<<<nbkt, 256, 0, stream>>>(pk, goff, dis, n);

        prep_wt<<<32, 256, 0, stream>>>(W1, Wt);
        mm1_mfma<<<mmBlk, 256, 0, stream>>>(x, Wt, dis, h1, hsb, n);

        kagg<<<nbkt, 256, 0, stream>>>(pk, goff, hsb, agg1, n);
        mid<<<featBlk, 256, 0, stream>>>(agg1, h1, hsb, dis, b1, W2, n);
        kagg<<<nbkt, 256, 0, stream>>>(pk, goff, hsb, outf, n);
        finalk<<<featBlk, 256, 0, stream>>>(outf, h1, dis, b2, eps, n);
    } else {
        // round-7 path
        int*            ideg = (int*)d_ws;
        float*          dis  = (float*)(ideg + n);
        float*          h1   = dis + n;
        float*          agg1 = h1 + (size_t)n * HID;
        unsigned short* hsb  = (unsigned short*)(agg1 + (size_t)n * HID);
        unsigned short* Wt   = hsb + (size_t)n * HID;

        size_t featBytes = (size_t)n * HID * sizeof(float);
        hipMemsetAsync(ideg, 0, (size_t)n * sizeof(int), stream);
        hipMemsetAsync(agg1, 0, featBytes, stream);
        hipMemsetAsync(outf, 0, featBytes, stream);

        int propBlk = (e * 16 + 255) / 256;
        prep_wt<<<32, 256, 0, stream>>>(W1, Wt);
        deg_count_int<<<eBlk, 256, 0, stream>>>(dsts, ideg, e);
        make_dis<<<nBlk, 256, 0, stream>>>(ideg, dis, n);
        mm1_mfma<<<mmBlk, 256, 0, stream>>>(x, Wt, dis, h1, hsb, n);
        prop<<<propBlk, 256, 0, stream>>>(srcs, dsts, hsb, agg1, e);
        mid<<<featBlk, 256, 0, stream>>>(agg1, h1, hsb, dis, b1, W2, n);
        prop<<<propBlk, 256, 0, stream>>>(srcs, dsts, hsb, outf, e);
        finalk<<<featBlk, 256, 0, stream>>>(outf, h1, dis, b2, eps, n);
    }
}

// Round 11
// 750.721 us; speedup vs baseline: 1.0205x; 1.0205x over previous
//
#include <hip/hip_runtime.h>
#include <hip/hip_bf16.h>

#define HID 16
#define NFEAT 512
#define BW 64           // nodes per bucket (dst >> 6)
#define CH 16384        // edges per histogram/scatter block
#define MAXB 2048       // max buckets supported by bucket path

typedef __attribute__((ext_vector_type(8))) short bf16x8;
typedef __attribute__((ext_vector_type(4))) float f32x4;

__device__ __forceinline__ unsigned short f2b_hw(float f) {
    __hip_bfloat16 h = __float2bfloat16(f);
    return *reinterpret_cast<unsigned short*>(&h);
}
__device__ __forceinline__ float b2f(unsigned short b) {
    return __uint_as_float(((unsigned)b) << 16);
}

// ================= bucket build =================
__global__ __launch_bounds__(1024) void khist(const int* __restrict__ dst,
                                              int* __restrict__ gcount, int e, int nbkt) {
    __shared__ int hist[MAXB];
    for (int t = threadIdx.x; t < nbkt; t += 1024) hist[t] = 0;
    __syncthreads();
    int base = blockIdx.x * CH;
#pragma unroll
    for (int k = 0; k < CH / 1024; ++k) {
        int i = base + k * 1024 + threadIdx.x;
        if (i < e) atomicAdd(&hist[dst[i] >> 6], 1);
    }
    __syncthreads();
    for (int t = threadIdx.x; t < nbkt; t += 1024)
        if (hist[t]) atomicAdd(&gcount[t], hist[t]);
}

__global__ __launch_bounds__(1024) void kscan(const int* __restrict__ gcount,
                                              int* __restrict__ goff,
                                              int* __restrict__ gcursor, int nbkt) {
    __shared__ int buf0[MAXB], buf1[MAXB];
    for (int t = threadIdx.x; t < MAXB; t += 1024) buf0[t] = (t < nbkt) ? gcount[t] : 0;
    __syncthreads();
    int* in = buf0; int* out = buf1;
    for (int d = 1; d < MAXB; d <<= 1) {
        for (int t = threadIdx.x; t < MAXB; t += 1024)
            out[t] = in[t] + (t >= d ? in[t - d] : 0);
        __syncthreads();
        int* tmp = in; in = out; out = tmp;
    }
    for (int t = threadIdx.x; t < nbkt; t += 1024) {
        int excl = in[t] - gcount[t];
        goff[t] = excl;
        gcursor[t] = excl;
    }
    if (threadIdx.x == 0) goff[nbkt] = in[nbkt - 1];
}

// LDS-presorted scatter of PACKED edges: pk = (src<<6) | (dst & 63).
__global__ __launch_bounds__(1024) void kscatter(const int* __restrict__ src,
                                                 const int* __restrict__ dst,
                                                 int* __restrict__ gcursor,
                                                 unsigned* __restrict__ pk, int e, int nbkt) {
    __shared__ int hist[MAXB];
    __shared__ int base[MAXB];
    for (int t = threadIdx.x; t < nbkt; t += 1024) hist[t] = 0;
    __syncthreads();
    int b0 = blockIdx.x * CH;
#pragma unroll
    for (int k = 0; k < CH / 1024; ++k) {
        int i = b0 + k * 1024 + threadIdx.x;
        if (i < e) atomicAdd(&hist[dst[i] >> 6], 1);
    }
    __syncthreads();
    for (int t = threadIdx.x; t < nbkt; t += 1024)
        base[t] = hist[t] ? atomicAdd(&gcursor[t], hist[t]) : 0;
    __syncthreads();
#pragma unroll
    for (int k = 0; k < CH / 1024; ++k) {
        int i = b0 + k * 1024 + threadIdx.x;
        if (i < e) {
            int d = dst[i];
            int pos = atomicAdd(&base[d >> 6], 1);   // LDS bump
            pk[pos] = ((unsigned)src[i] << 6) | (unsigned)(d & 63);
        }
    }
}

// ================= per-bucket degree =================
__global__ __launch_bounds__(256) void kdeg(const unsigned* __restrict__ pk,
                                            const int* __restrict__ goff,
                                            float* __restrict__ dis, int n) {
    __shared__ int cnt[BW];
    int b = blockIdx.x;
    if (threadIdx.x < BW) cnt[threadIdx.x] = 0;
    __syncthreads();
    int s0 = goff[b], s1 = goff[b + 1];
    for (int i = s0 + threadIdx.x; i < s1; i += 256)
        atomicAdd(&cnt[pk[i] & 63], 1);
    __syncthreads();
    if (threadIdx.x < BW) {
        int node = b * BW + threadIdx.x;
        if (node < n) dis[node] = rsqrtf(1.0f + (float)cnt[threadIdx.x]);
    }
}

// ================= W1 -> Wt (bf16 transposed) =================
__global__ __launch_bounds__(256) void prep_wt(const float* __restrict__ W1,
                                               unsigned short* __restrict__ Wt) {
    int i = blockIdx.x * 256 + threadIdx.x;   // 8192 = 16*512
    int j = i >> 9, k = i & 511;
    Wt[i] = f2b_hw(W1[k * HID + j]);
}

// ================= h1 = x @ W1 via MFMA (proven) =================
__global__ __launch_bounds__(256) void mm1_mfma(const float* __restrict__ x,
                                                const unsigned short* __restrict__ Wt,
                                                const float* __restrict__ dis,
                                                float* __restrict__ h1,
                                                unsigned short* __restrict__ hsb, int n) {
    int wid  = threadIdx.x >> 6;
    int lane = threadIdx.x & 63;
    int base = (blockIdx.x * 4 + wid) * 16;
    if (base >= n) return;
    int lrow = lane & 15;
    int kg   = lane >> 4;

    bf16x8 bfr[16];
#pragma unroll
    for (int t = 0; t < 16; ++t)
        bfr[t] = *(const bf16x8*)(Wt + lrow * NFEAT + t * 32 + kg * 8);

    int row = base + lrow;
    bool ok = (row < n);
    const float* xr = x + (size_t)(ok ? row : 0) * NFEAT;

    f32x4 acc = {0.f, 0.f, 0.f, 0.f};
#pragma unroll
    for (int t = 0; t < 16; ++t) {
        float4 u0 = *(const float4*)(xr + t * 32 + kg * 8);
        float4 u1 = *(const float4*)(xr + t * 32 + kg * 8 + 4);
        if (!ok) { u0 = make_float4(0,0,0,0); u1 = make_float4(0,0,0,0); }
        union { bf16x8 v; unsigned short u[8]; } A;
        A.u[0] = f2b_hw(u0.x); A.u[1] = f2b_hw(u0.y);
        A.u[2] = f2b_hw(u0.z); A.u[3] = f2b_hw(u0.w);
        A.u[4] = f2b_hw(u1.x); A.u[5] = f2b_hw(u1.y);
        A.u[6] = f2b_hw(u1.z); A.u[7] = f2b_hw(u1.w);
        acc = __builtin_amdgcn_mfma_f32_16x16x32_bf16(A.v, bfr[t], acc, 0, 0, 0);
    }

#pragma unroll
    for (int q = 0; q < 4; ++q) {
        int orow = base + kg * 4 + q;
        if (orow < n) {
            float v = acc[q];
            h1[(size_t)orow * HID + lrow] = v;
            hsb[(size_t)orow * HID + lrow] = f2b_hw(v * dis[orow]);
        }
    }
}

// ================= per-bucket aggregation, 1-lane-per-edge =================
// Rounds 8-10 all hit ~305us regardless of inner schedule: the cost is the
// NUMBER of scattered vector-load instructions (64 lane-addresses of TA-port
// occupancy each). 16-lane/edge = 800K gather instrs/pass. Here: 1 lane per
// edge, whole 32B row via 2x dwordx4 -> 100K gather instrs (8x fewer), then
// 16 LDS ds_add_f32. pk reads are coalesced; no staging, no chunk barriers.
__global__ __launch_bounds__(256) void kagg(const unsigned* __restrict__ pk,
                                            const int* __restrict__ goff,
                                            const unsigned short* __restrict__ hsb,
                                            float* __restrict__ out, int n) {
    __shared__ float acc[BW * 17];
    int b = blockIdx.x;
    for (int t = threadIdx.x; t < BW * 17; t += 256) acc[t] = 0.f;
    __syncthreads();
    int s0 = goff[b], s1 = goff[b + 1];
    for (int i = s0 + threadIdx.x; i < s1; i += 256) {
        unsigned v = pk[i];
        const uint4* row = (const uint4*)(hsb + (size_t)(v >> 6) * HID);  // 16B aligned
        uint4 r0 = row[0];
        uint4 r1 = row[1];
        float* a = acc + (v & 63u) * 17;
        atomicAdd(a + 0,  b2f((unsigned short)(r0.x)));
        atomicAdd(a + 1,  b2f((unsigned short)(r0.x >> 16)));
        atomicAdd(a + 2,  b2f((unsigned short)(r0.y)));
        atomicAdd(a + 3,  b2f((unsigned short)(r0.y >> 16)));
        atomicAdd(a + 4,  b2f((unsigned short)(r0.z)));
        atomicAdd(a + 5,  b2f((unsigned short)(r0.z >> 16)));
        atomicAdd(a + 6,  b2f((unsigned short)(r0.w)));
        atomicAdd(a + 7,  b2f((unsigned short)(r0.w >> 16)));
        atomicAdd(a + 8,  b2f((unsigned short)(r1.x)));
        atomicAdd(a + 9,  b2f((unsigned short)(r1.x >> 16)));
        atomicAdd(a + 10, b2f((unsigned short)(r1.y)));
        atomicAdd(a + 11, b2f((unsigned short)(r1.y >> 16)));
        atomicAdd(a + 12, b2f((unsigned short)(r1.z)));
        atomicAdd(a + 13, b2f((unsigned short)(r1.z >> 16)));
        atomicAdd(a + 14, b2f((unsigned short)(r1.w)));
        atomicAdd(a + 15, b2f((unsigned short)(r1.w >> 16)));
    }
    __syncthreads();
    int g = threadIdx.x >> 4, j = threadIdx.x & 15;
#pragma unroll
    for (int r0_ = 0; r0_ < BW; r0_ += 16) {
        int r = r0_ + g;
        int node = b * BW + r;
        if (node < n) out[(size_t)node * HID + j] = acc[r * 17 + j];
    }
}

// ================= fused middle / final =================
__global__ __launch_bounds__(256) void mid(const float* __restrict__ agg1,
                                           float* __restrict__ h1,
                                           unsigned short* __restrict__ hsb,
                                           const float* __restrict__ dis,
                                           const float* __restrict__ b1,
                                           const float* __restrict__ W2, int n) {
    __shared__ float W2s[HID * HID];
    W2s[threadIdx.x] = W2[threadIdx.x];
    __syncthreads();
    int idx = blockIdx.x * 256 + threadIdx.x;
    int v = idx >> 4, j = idx & 15;
    if (v >= n) return;
    float dn = dis[v];
    float a = dn * agg1[idx] + dn * dn * h1[idx] + b1[j];
    float hv = fmaxf(a, 0.f);
    float h2 = 0.f;
#pragma unroll
    for (int k = 0; k < HID; ++k)
        h2 += __shfl(hv, k, HID) * W2s[k * HID + j];
    h1[idx] = h2;
    hsb[idx] = f2b_hw(h2 * dn);
}

__global__ __launch_bounds__(256) void finalk(float* __restrict__ out,
                                              const float* __restrict__ h2,
                                              const float* __restrict__ dis,
                                              const float* __restrict__ b2,
                                              const float* __restrict__ eps, int n) {
    int idx = blockIdx.x * 256 + threadIdx.x;
    int v = idx >> 4, j = idx & 15;
    if (v >= n) return;
    float dn = dis[v];
    float z = dn * out[idx] + dn * dn * h2[idx] + b2[j];
    out[idx] = z + eps[idx] * expf(0.5f * z);
}

// ================= fallback (round-7 atomic path) =================
__global__ __launch_bounds__(256) void deg_count_int(const int* __restrict__ dst,
                                                     int* __restrict__ ideg, int e) {
    int i = blockIdx.x * 256 + threadIdx.x;
    if (i < e) atomicAdd(&ideg[dst[i]], 1);
}
__global__ __launch_bounds__(256) void make_dis(const int* __restrict__ ideg,
                                                float* __restrict__ dis, int n) {
    int i = blockIdx.x * 256 + threadIdx.x;
    if (i < n) dis[i] = rsqrtf(1.0f + (float)ideg[i]);
}
__global__ __launch_bounds__(256) void prop(const int* __restrict__ src,
                                            const int* __restrict__ dst,
                                            const unsigned short* __restrict__ hsb,
                                            float* __restrict__ agg, int e) {
    int idx = blockIdx.x * 256 + threadIdx.x;
    int ed = idx >> 4, j = idx & 15;
    if (ed >= e) return;
    int s = src[ed], d = dst[ed];
    atomicAdd(&agg[(size_t)d * HID + j], b2f(hsb[(size_t)s * HID + j]));
}

static inline size_t al64(size_t x) { return (x + 63) & ~(size_t)63; }

extern "C" void kernel_launch(void* const* d_in, const int* in_sizes, int n_in,
                              void* d_out, int out_size, void* d_ws, size_t ws_size,
                              hipStream_t stream) {
    const float* x   = (const float*)d_in[0];
    const float* W1  = (const float*)d_in[1];
    const float* b1  = (const float*)d_in[2];
    const float* W2  = (const float*)d_in[3];
    const float* b2  = (const float*)d_in[4];
    const float* eps = (const float*)d_in[5];
    const int*   ei  = (const int*)d_in[6];

    int n = in_sizes[5] / HID;   // 100000
    int e = in_sizes[6] / 2;     // 3200000
    const int* srcs = ei;
    const int* dsts = ei + e;
    float* outf = (float*)d_out;

    int nbkt    = (n + BW - 1) / BW;         // 1563
    int nBlk    = (n + 255) / 256;
    int eBlk    = (e + 255) / 256;
    int mmBlk   = (n + 63) / 64;
    int featBlk = (n * 16 + 255) / 256;
    int chBlk   = (e + CH - 1) / CH;         // 196

    // ws layout, every region 64B-aligned (hsb/Wt need >=16B for dwordx4/bf16x8):
    char* wp = (char*)d_ws;
    size_t o_pk   = 0;
    size_t o_hsb  = al64(o_pk   + (size_t)e * 4);
    size_t o_h1   = al64(o_hsb  + (size_t)n * HID * 2);
    size_t o_agg1 = al64(o_h1   + (size_t)n * HID * 4);
    size_t o_dis  = al64(o_agg1 + (size_t)n * HID * 4);
    size_t o_gc   = al64(o_dis  + (size_t)n * 4);
    size_t o_go   = al64(o_gc   + (size_t)(MAXB + 2) * 4);
    size_t o_gu   = al64(o_go   + (size_t)(MAXB + 2) * 4);
    size_t o_wt   = al64(o_gu   + (size_t)(MAXB + 2) * 4);
    size_t need   = o_wt + 8192 * 2;
    bool bucketPath = (nbkt <= MAXB) && ((size_t)n < (1u << 26)) && (ws_size >= need);

    if (bucketPath) {
        unsigned*       pk      = (unsigned*)(wp + o_pk);
        unsigned short* hsb     = (unsigned short*)(wp + o_hsb);
        float*          h1      = (float*)(wp + o_h1);
        float*          agg1    = (float*)(wp + o_agg1);
        float*          dis     = (float*)(wp + o_dis);
        int*            gcount  = (int*)(wp + o_gc);
        int*            goff    = (int*)(wp + o_go);
        int*            gcursor = (int*)(wp + o_gu);
        unsigned short* Wt      = (unsigned short*)(wp + o_wt);

        hipMemsetAsync(gcount, 0, (size_t)(MAXB + 2) * 4, stream);
        khist<<<chBlk, 1024, 0, stream>>>(dsts, gcount, e, nbkt);
        kscan<<<1, 1024, 0, stream>>>(gcount, goff, gcursor, nbkt);
        kscatter<<<chBlk, 1024, 0, stream>>>(srcs, dsts, gcursor, pk, e, nbkt);
        kdeg<<<nbkt, 256, 0, stream>>>(pk, goff, dis, n);

        prep_wt<<<32, 256, 0, stream>>>(W1, Wt);
        mm1_mfma<<<mmBlk, 256, 0, stream>>>(x, Wt, dis, h1, hsb, n);

        kagg<<<nbkt, 256, 0, stream>>>(pk, goff, hsb, agg1, n);
        mid<<<featBlk, 256, 0, stream>>>(agg1, h1, hsb, dis, b1, W2, n);
        kagg<<<nbkt, 256, 0, stream>>>(pk, goff, hsb, outf, n);
        finalk<<<featBlk, 256, 0, stream>>>(outf, h1, dis, b2, eps, n);
    } else {
        // round-7 path (global fp32 atomics, 16 lanes/edge)
        char* fp = (char*)d_ws;
        size_t f_ideg = 0;
        size_t f_dis  = al64(f_ideg + (size_t)n * 4);
        size_t f_h1   = al64(f_dis  + (size_t)n * 4);
        size_t f_agg1 = al64(f_h1   + (size_t)n * HID * 4);
        size_t f_hsb  = al64(f_agg1 + (size_t)n * HID * 4);
        size_t f_wt   = al64(f_hsb  + (size_t)n * HID * 2);
        int*            ideg = (int*)(fp + f_ideg);
        float*          dis  = (float*)(fp + f_dis);
        float*          h1   = (float*)(fp + f_h1);
        float*          agg1 = (float*)(fp + f_agg1);
        unsigned short* hsb  = (unsigned short*)(fp + f_hsb);
        unsigned short* Wt   = (unsigned short*)(fp + f_wt);

        size_t featBytes = (size_t)n * HID * sizeof(float);
        hipMemsetAsync(ideg, 0, (size_t)n * sizeof(int), stream);
        hipMemsetAsync(agg1, 0, featBytes, stream);
        hipMemsetAsync(outf, 0, featBytes, stream);

        int propBlk = (e * 16 + 255) / 256;
        prep_wt<<<32, 256, 0, stream>>>(W1, Wt);
        deg_count_int<<<eBlk, 256, 0, stream>>>(dsts, ideg, e);
        make_dis<<<nBlk, 256, 0, stream>>>(ideg, dis, n);
        mm1_mfma<<<mmBlk, 256, 0, stream>>>(x, Wt, dis, h1, hsb, n);
        prop<<<propBlk, 256, 0, stream>>>(srcs, dsts, hsb, agg1, e);
        mid<<<featBlk, 256, 0, stream>>>(agg1, h1, hsb, dis, b1, W2, n);
        prop<<<propBlk, 256, 0, stream>>>(srcs, dsts, hsb, outf, e);
        finalk<<<featBlk, 256, 0, stream>>>(outf, h1, dis, b2, eps, n);
    }
}

// Round 12
// 625.495 us; speedup vs baseline: 1.2248x; 1.2002x over previous
//
#include <hip/hip_runtime.h>
#include <hip/hip_bf16.h>

#define HID 16
#define NFEAT 512
#define WBINS 16000     // nodes per degree-histogram window (64KB LDS)
#define BPW   16        // slice-blocks per window

typedef __attribute__((ext_vector_type(8))) short bf16x8;
typedef __attribute__((ext_vector_type(4))) float f32x4;

__device__ __forceinline__ unsigned short f2b_hw(float f) {
    __hip_bfloat16 h = __float2bfloat16(f);
    return *reinterpret_cast<unsigned short*>(&h);
}
__device__ __forceinline__ float b2f(unsigned short b) {
    return __uint_as_float(((unsigned)b) << 16);
}

// ================= degree via windowed LDS histogram =================
// Replaces 3.2M scattered global int atomics (~130us) with coalesced reads +
// LDS atomics + consecutive-address (line-merged) flush atomics.
__global__ __launch_bounds__(256) void ndeg(const int* __restrict__ dst,
                                            int* __restrict__ ideg, int e, int n) {
    __shared__ int bins[WBINS];
    int win = blockIdx.x / BPW;
    int sl  = blockIdx.x % BPW;
    int lo  = win * WBINS;
    for (int t = threadIdx.x; t < WBINS; t += 256) bins[t] = 0;
    __syncthreads();
    int per = (e + BPW - 1) / BPW;
    int i0 = sl * per;
    int i1 = min(e, i0 + per);
    for (int i = i0 + threadIdx.x; i < i1; i += 256) {
        int d = dst[i] - lo;
        if ((unsigned)d < (unsigned)WBINS) atomicAdd(&bins[d], 1);
    }
    __syncthreads();
    for (int t = threadIdx.x; t < WBINS; t += 256) {
        int node = lo + t;
        if (node < n && bins[t]) atomicAdd(&ideg[node], bins[t]);   // coalesced
    }
}

__global__ __launch_bounds__(256) void make_dis(const int* __restrict__ ideg,
                                                float* __restrict__ dis, int n) {
    int i = blockIdx.x * 256 + threadIdx.x;
    if (i < n) dis[i] = rsqrtf(1.0f + (float)ideg[i]);
}

// ================= W1 -> Wt (bf16 transposed) =================
__global__ __launch_bounds__(256) void prep_wt(const float* __restrict__ W1,
                                               unsigned short* __restrict__ Wt) {
    int i = blockIdx.x * 256 + threadIdx.x;   // 8192 = 16*512
    int j = i >> 9, k = i & 511;
    Wt[i] = f2b_hw(W1[k * HID + j]);
}

// ================= h1 = x @ W1 via MFMA (proven round 7) =================
__global__ __launch_bounds__(256) void mm1_mfma(const float* __restrict__ x,
                                                const unsigned short* __restrict__ Wt,
                                                const float* __restrict__ dis,
                                                float* __restrict__ h1,
                                                unsigned short* __restrict__ hsb, int n) {
    int wid  = threadIdx.x >> 6;
    int lane = threadIdx.x & 63;
    int base = (blockIdx.x * 4 + wid) * 16;
    if (base >= n) return;
    int lrow = lane & 15;
    int kg   = lane >> 4;

    bf16x8 bfr[16];
#pragma unroll
    for (int t = 0; t < 16; ++t)
        bfr[t] = *(const bf16x8*)(Wt + lrow * NFEAT + t * 32 + kg * 8);

    int row = base + lrow;
    bool ok = (row < n);
    const float* xr = x + (size_t)(ok ? row : 0) * NFEAT;

    f32x4 acc = {0.f, 0.f, 0.f, 0.f};
#pragma unroll
    for (int t = 0; t < 16; ++t) {
        float4 u0 = *(const float4*)(xr + t * 32 + kg * 8);
        float4 u1 = *(const float4*)(xr + t * 32 + kg * 8 + 4);
        if (!ok) { u0 = make_float4(0,0,0,0); u1 = make_float4(0,0,0,0); }
        union { bf16x8 v; unsigned short u[8]; } A;
        A.u[0] = f2b_hw(u0.x); A.u[1] = f2b_hw(u0.y);
        A.u[2] = f2b_hw(u0.z); A.u[3] = f2b_hw(u0.w);
        A.u[4] = f2b_hw(u1.x); A.u[5] = f2b_hw(u1.y);
        A.u[6] = f2b_hw(u1.z); A.u[7] = f2b_hw(u1.w);
        acc = __builtin_amdgcn_mfma_f32_16x16x32_bf16(A.v, bfr[t], acc, 0, 0, 0);
    }

#pragma unroll
    for (int q = 0; q < 4; ++q) {
        int orow = base + kg * 4 + q;
        if (orow < n) {
            float v = acc[q];
            h1[(size_t)orow * HID + lrow] = v;
            hsb[(size_t)orow * HID + lrow] = f2b_hw(v * dis[orow]);
        }
    }
}

// ================= propagation (proven: 169us/pass) =================
// 16 consecutive lanes per edge, one fp32 atomic per lane: 1 read txn + 1
// line-RMW per edge, 51.2M threads give full queue depth.
__global__ __launch_bounds__(256) void prop(const int* __restrict__ src,
                                            const int* __restrict__ dst,
                                            const unsigned short* __restrict__ hsb,
                                            float* __restrict__ agg, int e) {
    int idx = blockIdx.x * 256 + threadIdx.x;   // e*16 = 51.2M < 2^31
    int ed = idx >> 4, j = idx & 15;
    if (ed >= e) return;
    int s = src[ed], d = dst[ed];
    atomicAdd(&agg[(size_t)d * HID + j], b2f(hsb[(size_t)s * HID + j]));
}

// ================= fused middle / final (proven) =================
__global__ __launch_bounds__(256) void mid(const float* __restrict__ agg1,
                                           float* __restrict__ h1,
                                           unsigned short* __restrict__ hsb,
                                           const float* __restrict__ dis,
                                           const float* __restrict__ b1,
                                           const float* __restrict__ W2, int n) {
    __shared__ float W2s[HID * HID];
    W2s[threadIdx.x] = W2[threadIdx.x];
    __syncthreads();
    int idx = blockIdx.x * 256 + threadIdx.x;
    int v = idx >> 4, j = idx & 15;
    if (v >= n) return;
    float dn = dis[v];
    float a = dn * agg1[idx] + dn * dn * h1[idx] + b1[j];
    float hv = fmaxf(a, 0.f);
    float h2 = 0.f;
#pragma unroll
    for (int k = 0; k < HID; ++k)
        h2 += __shfl(hv, k, HID) * W2s[k * HID + j];
    h1[idx] = h2;
    hsb[idx] = f2b_hw(h2 * dn);
}

__global__ __launch_bounds__(256) void finalk(float* __restrict__ out,
                                              const float* __restrict__ h2,
                                              const float* __restrict__ dis,
                                              const float* __restrict__ b2,
                                              const float* __restrict__ eps, int n) {
    int idx = blockIdx.x * 256 + threadIdx.x;
    int v = idx >> 4, j = idx & 15;
    if (v >= n) return;
    float dn = dis[v];
    float z = dn * out[idx] + dn * dn * h2[idx] + b2[j];
    out[idx] = z + eps[idx] * expf(0.5f * z);
}

static inline size_t al64(size_t x) { return (x + 63) & ~(size_t)63; }

extern "C" void kernel_launch(void* const* d_in, const int* in_sizes, int n_in,
                              void* d_out, int out_size, void* d_ws, size_t ws_size,
                              hipStream_t stream) {
    const float* x   = (const float*)d_in[0];
    const float* W1  = (const float*)d_in[1];
    const float* b1  = (const float*)d_in[2];
    const float* W2  = (const float*)d_in[3];
    const float* b2  = (const float*)d_in[4];
    const float* eps = (const float*)d_in[5];
    const int*   ei  = (const int*)d_in[6];

    int n = in_sizes[5] / HID;   // 100000
    int e = in_sizes[6] / 2;     // 3200000
    const int* srcs = ei;
    const int* dsts = ei + e;
    float* outf = (float*)d_out;

    // ws layout, 64B-aligned regions
    char* wp = (char*)d_ws;
    size_t o_ideg = 0;
    size_t o_dis  = al64(o_ideg + (size_t)n * 4);
    size_t o_h1   = al64(o_dis  + (size_t)n * 4);
    size_t o_agg1 = al64(o_h1   + (size_t)n * HID * 4);
    size_t o_hsb  = al64(o_agg1 + (size_t)n * HID * 4);
    size_t o_wt   = al64(o_hsb  + (size_t)n * HID * 2);

    int*            ideg = (int*)(wp + o_ideg);
    float*          dis  = (float*)(wp + o_dis);
    float*          h1   = (float*)(wp + o_h1);
    float*          agg1 = (float*)(wp + o_agg1);
    unsigned short* hsb  = (unsigned short*)(wp + o_hsb);
    unsigned short* Wt   = (unsigned short*)(wp + o_wt);

    size_t featBytes = (size_t)n * HID * sizeof(float);
    hipMemsetAsync(ideg, 0, (size_t)n * sizeof(int), stream);
    hipMemsetAsync(agg1, 0, featBytes, stream);
    hipMemsetAsync(outf, 0, featBytes, stream);

    int nBlk    = (n + 255) / 256;
    int mmBlk   = (n + 63) / 64;
    int featBlk = (n * 16 + 255) / 256;
    int propBlk = (e * 16 + 255) / 256;
    int nwin    = (n + WBINS - 1) / WBINS;   // 7

    prep_wt<<<32, 256, 0, stream>>>(W1, Wt);
    ndeg<<<nwin * BPW, 256, 0, stream>>>(dsts, ideg, e, n);
    make_dis<<<nBlk, 256, 0, stream>>>(ideg, dis, n);

    mm1_mfma<<<mmBlk, 256, 0, stream>>>(x, Wt, dis, h1, hsb, n);

    prop<<<propBlk, 256, 0, stream>>>(srcs, dsts, hsb, agg1, e);
    mid<<<featBlk, 256, 0, stream>>>(agg1, h1, hsb, dis, b1, W2, n);
    prop<<<propBlk, 256, 0, stream>>>(srcs, dsts, hsb, outf, e);
    finalk<<<featBlk, 256, 0, stream>>>(outf, h1, dis, b2, eps, n);
}

// Round 13
// 424.797 us; speedup vs baseline: 1.8035x; 1.4725x over previous
//
#include <hip/hip_runtime.h>
#include <hip/hip_bf16.h>

#define HID 16
#define NFEAT 512
#define BW 64           // nodes per bucket (dst >> 6)
#define CH 16384        // edges per histogram/scatter block
#define MAXB 2048       // max buckets supported by bucket path
#define SCAP 5120       // ksort LDS staging capacity (int2)

typedef __attribute__((ext_vector_type(8))) short bf16x8;
typedef __attribute__((ext_vector_type(4))) float f32x4;

__device__ __forceinline__ unsigned short f2b_hw(float f) {
    __hip_bfloat16 h = __float2bfloat16(f);
    return *reinterpret_cast<unsigned short*>(&h);
}
__device__ __forceinline__ float b2f(unsigned short b) {
    return __uint_as_float(((unsigned)b) << 16);
}

// ================= bucket build (proven round 8) =================
__global__ __launch_bounds__(1024) void khist(const int* __restrict__ dst,
                                              int* __restrict__ gcount, int e, int nbkt) {
    __shared__ int hist[MAXB];
    for (int t = threadIdx.x; t < nbkt; t += 1024) hist[t] = 0;
    __syncthreads();
    int base = blockIdx.x * CH;
#pragma unroll
    for (int k = 0; k < CH / 1024; ++k) {
        int i = base + k * 1024 + threadIdx.x;
        if (i < e) atomicAdd(&hist[dst[i] >> 6], 1);
    }
    __syncthreads();
    for (int t = threadIdx.x; t < nbkt; t += 1024)
        if (hist[t]) atomicAdd(&gcount[t], hist[t]);
}

__global__ __launch_bounds__(1024) void kscan(const int* __restrict__ gcount,
                                              int* __restrict__ goff,
                                              int* __restrict__ gcursor, int nbkt) {
    __shared__ int buf0[MAXB], buf1[MAXB];
    for (int t = threadIdx.x; t < MAXB; t += 1024) buf0[t] = (t < nbkt) ? gcount[t] : 0;
    __syncthreads();
    int* in = buf0; int* out = buf1;
    for (int d = 1; d < MAXB; d <<= 1) {
        for (int t = threadIdx.x; t < MAXB; t += 1024)
            out[t] = in[t] + (t >= d ? in[t - d] : 0);
        __syncthreads();
        int* tmp = in; in = out; out = tmp;
    }
    for (int t = threadIdx.x; t < nbkt; t += 1024) {
        int excl = in[t] - gcount[t];
        goff[t] = excl;
        gcursor[t] = excl;
    }
    if (threadIdx.x == 0) goff[nbkt] = in[nbkt - 1];
}

__global__ __launch_bounds__(1024) void kscatter(const int* __restrict__ src,
                                                 const int* __restrict__ dst,
                                                 int* __restrict__ gcursor,
                                                 int2* __restrict__ pairs, int e, int nbkt) {
    __shared__ int hist[MAXB];
    __shared__ int base[MAXB];
    for (int t = threadIdx.x; t < nbkt; t += 1024) hist[t] = 0;
    __syncthreads();
    int b0 = blockIdx.x * CH;
#pragma unroll
    for (int k = 0; k < CH / 1024; ++k) {
        int i = b0 + k * 1024 + threadIdx.x;
        if (i < e) atomicAdd(&hist[dst[i] >> 6], 1);
    }
    __syncthreads();
    for (int t = threadIdx.x; t < nbkt; t += 1024)
        base[t] = hist[t] ? atomicAdd(&gcursor[t], hist[t]) : 0;
    __syncthreads();
#pragma unroll
    for (int k = 0; k < CH / 1024; ++k) {
        int i = b0 + k * 1024 + threadIdx.x;
        if (i < e) {
            int d = dst[i];
            int pos = atomicAdd(&base[d >> 6], 1);   // LDS bump
            pairs[pos] = make_int2(src[i], d);
        }
    }
}

// ================= per-bucket counting sort by dst + dis =================
// One block per 64-node bucket. Also computes dis (replaces deg_count+make_dis,
// the old 130us scattered-atomic pass). Oversized buckets stay unsorted
// (prop_s merge is opportunistic -> still correct).
__global__ __launch_bounds__(256) void ksort(int2* __restrict__ pairs,
                                             const int* __restrict__ goff,
                                             float* __restrict__ dis, int n) {
    __shared__ int cnt[BW];
    __shared__ int ofs[BW];
    __shared__ int2 stg[SCAP];
    int b = blockIdx.x;
    int s0 = goff[b], s1 = goff[b + 1];
    int m = s1 - s0;
    if (threadIdx.x < BW) cnt[threadIdx.x] = 0;
    __syncthreads();
    bool fits = (m <= SCAP);
    if (fits) {
        for (int i = threadIdx.x; i < m; i += 256) {
            int2 p = pairs[s0 + i];
            stg[i] = p;
            atomicAdd(&cnt[p.y & (BW - 1)], 1);
        }
    } else {
        for (int i = threadIdx.x; i < m; i += 256)
            atomicAdd(&cnt[pairs[s0 + i].y & (BW - 1)], 1);
    }
    __syncthreads();
    if (threadIdx.x < BW) {
        int node = b * BW + threadIdx.x;
        if (node < n) dis[node] = rsqrtf(1.0f + (float)cnt[threadIdx.x]);
        // exclusive prefix over 64 bins (single wave, shfl scan)
        int v = cnt[threadIdx.x];
        int inc = v;
        for (int d = 1; d < 64; d <<= 1) {
            int o = __shfl_up(inc, d);
            if (threadIdx.x >= (unsigned)d) inc += o;
        }
        ofs[threadIdx.x] = inc - v;
    }
    __syncthreads();
    if (fits) {
        for (int i = threadIdx.x; i < m; i += 256) {
            int2 p = stg[i];
            int pos = atomicAdd(&ofs[p.y & (BW - 1)], 1);
            pairs[s0 + pos] = p;
        }
    }
}

// ================= W1 -> Wt (bf16 transposed) =================
__global__ __launch_bounds__(256) void prep_wt(const float* __restrict__ W1,
                                               unsigned short* __restrict__ Wt) {
    int i = blockIdx.x * 256 + threadIdx.x;   // 8192 = 16*512
    int j = i >> 9, k = i & 511;
    Wt[i] = f2b_hw(W1[k * HID + j]);
}

// ================= h1 = x @ W1 via MFMA (proven round 7) =================
__global__ __launch_bounds__(256) void mm1_mfma(const float* __restrict__ x,
                                                const unsigned short* __restrict__ Wt,
                                                const float* __restrict__ dis,
                                                float* __restrict__ h1,
                                                unsigned short* __restrict__ hsb, int n) {
    int wid  = threadIdx.x >> 6;
    int lane = threadIdx.x & 63;
    int base = (blockIdx.x * 4 + wid) * 16;
    if (base >= n) return;
    int lrow = lane & 15;
    int kg   = lane >> 4;

    bf16x8 bfr[16];
#pragma unroll
    for (int t = 0; t < 16; ++t)
        bfr[t] = *(const bf16x8*)(Wt + lrow * NFEAT + t * 32 + kg * 8);

    int row = base + lrow;
    bool ok = (row < n);
    const float* xr = x + (size_t)(ok ? row : 0) * NFEAT;

    f32x4 acc = {0.f, 0.f, 0.f, 0.f};
#pragma unroll
    for (int t = 0; t < 16; ++t) {
        float4 u0 = *(const float4*)(xr + t * 32 + kg * 8);
        float4 u1 = *(const float4*)(xr + t * 32 + kg * 8 + 4);
        if (!ok) { u0 = make_float4(0,0,0,0); u1 = make_float4(0,0,0,0); }
        union { bf16x8 v; unsigned short u[8]; } A;
        A.u[0] = f2b_hw(u0.x); A.u[1] = f2b_hw(u0.y);
        A.u[2] = f2b_hw(u0.z); A.u[3] = f2b_hw(u0.w);
        A.u[4] = f2b_hw(u1.x); A.u[5] = f2b_hw(u1.y);
        A.u[6] = f2b_hw(u1.z); A.u[7] = f2b_hw(u1.w);
        acc = __builtin_amdgcn_mfma_f32_16x16x32_bf16(A.v, bfr[t], acc, 0, 0, 0);
    }

#pragma unroll
    for (int q = 0; q < 4; ++q) {
        int orow = base + kg * 4 + q;
        if (orow < n) {
            float v = acc[q];
            h1[(size_t)orow * HID + lrow] = v;
            hsb[(size_t)orow * HID + lrow] = f2b_hw(v * dis[orow]);
        }
    }
}

// ================= propagation over dst-sorted pairs, in-wave run merge =====
// Wave = 4 edge slots x 16 features. Sorted dsts => equal dsts are adjacent.
// Guarded suffix segmented scan (2 shfl_down steps) gives each run-leader the
// full run sum; only leaders issue the atomic -> ~3.5x fewer RMW txns.
// Works (unmerged) on unsorted data too.
__global__ __launch_bounds__(256) void prop_s(const int2* __restrict__ pairs,
                                              const unsigned short* __restrict__ hsb,
                                              float* __restrict__ agg, int e) {
    int wave = blockIdx.x * 4 + (threadIdx.x >> 6);
    int lane = threadIdx.x & 63;
    int slot = lane >> 4, j = lane & 15;
    int edge = wave * 4 + slot;

    int d = -1;
    float val = 0.f;
    if (edge < e) {
        int2 p = pairs[edge];
        d = p.y;
        val = b2f(hsb[(size_t)p.x * HID + j]);
    }
    // suffix segmented scan over slots
    int   dn1 = __shfl_down(d, 16);
    float vn1 = __shfl_down(val, 16);
    if (slot < 3 && dn1 == d) val += vn1;
    int   dn2 = __shfl_down(d, 32);
    float vn2 = __shfl_down(val, 32);
    if (slot < 2 && dn2 == d) val += vn2;
    // leader = first slot of its run
    int dp = __shfl_up(d, 16);
    bool leader = (d >= 0) && (slot == 0 || dp != d);
    if (leader) atomicAdd(&agg[(size_t)d * HID + j], val);
}

// ================= fused middle / final (proven) =================
__global__ __launch_bounds__(256) void mid(const float* __restrict__ agg1,
                                           float* __restrict__ h1,
                                           unsigned short* __restrict__ hsb,
                                           const float* __restrict__ dis,
                                           const float* __restrict__ b1,
                                           const float* __restrict__ W2, int n) {
    __shared__ float W2s[HID * HID];
    W2s[threadIdx.x] = W2[threadIdx.x];
    __syncthreads();
    int idx = blockIdx.x * 256 + threadIdx.x;
    int v = idx >> 4, j = idx & 15;
    if (v >= n) return;
    float dn = dis[v];
    float a = dn * agg1[idx] + dn * dn * h1[idx] + b1[j];
    float hv = fmaxf(a, 0.f);
    float h2 = 0.f;
#pragma unroll
    for (int k = 0; k < HID; ++k)
        h2 += __shfl(hv, k, HID) * W2s[k * HID + j];
    h1[idx] = h2;
    hsb[idx] = f2b_hw(h2 * dn);
}

__global__ __launch_bounds__(256) void finalk(float* __restrict__ out,
                                              const float* __restrict__ h2,
                                              const float* __restrict__ dis,
                                              const float* __restrict__ b2,
                                              const float* __restrict__ eps, int n) {
    int idx = blockIdx.x * 256 + threadIdx.x;
    int v = idx >> 4, j = idx & 15;
    if (v >= n) return;
    float dn = dis[v];
    float z = dn * out[idx] + dn * dn * h2[idx] + b2[j];
    out[idx] = z + eps[idx] * expf(0.5f * z);
}

// ================= fallback (round-7 atomic path) =================
__global__ __launch_bounds__(256) void deg_count_int(const int* __restrict__ dst,
                                                     int* __restrict__ ideg, int e) {
    int i = blockIdx.x * 256 + threadIdx.x;
    if (i < e) atomicAdd(&ideg[dst[i]], 1);
}
__global__ __launch_bounds__(256) void make_dis(const int* __restrict__ ideg,
                                                float* __restrict__ dis, int n) {
    int i = blockIdx.x * 256 + threadIdx.x;
    if (i < n) dis[i] = rsqrtf(1.0f + (float)ideg[i]);
}
__global__ __launch_bounds__(256) void prop(const int* __restrict__ src,
                                            const int* __restrict__ dst,
                                            const unsigned short* __restrict__ hsb,
                                            float* __restrict__ agg, int e) {
    int idx = blockIdx.x * 256 + threadIdx.x;
    int ed = idx >> 4, j = idx & 15;
    if (ed >= e) return;
    int s = src[ed], d = dst[ed];
    atomicAdd(&agg[(size_t)d * HID + j], b2f(hsb[(size_t)s * HID + j]));
}

static inline size_t al64(size_t x) { return (x + 63) & ~(size_t)63; }

extern "C" void kernel_launch(void* const* d_in, const int* in_sizes, int n_in,
                              void* d_out, int out_size, void* d_ws, size_t ws_size,
                              hipStream_t stream) {
    const float* x   = (const float*)d_in[0];
    const float* W1  = (const float*)d_in[1];
    const float* b1  = (const float*)d_in[2];
    const float* W2  = (const float*)d_in[3];
    const float* b2  = (const float*)d_in[4];
    const float* eps = (const float*)d_in[5];
    const int*   ei  = (const int*)d_in[6];

    int n = in_sizes[5] / HID;   // 100000
    int e = in_sizes[6] / 2;     // 3200000
    const int* srcs = ei;
    const int* dsts = ei + e;
    float* outf = (float*)d_out;

    int nbkt    = (n + BW - 1) / BW;         // 1563
    int nBlk    = (n + 255) / 256;
    int mmBlk   = (n + 63) / 64;
    int featBlk = (n * 16 + 255) / 256;
    int chBlk   = (e + CH - 1) / CH;         // 196

    // ws layout, 64B-aligned regions
    char* wp = (char*)d_ws;
    size_t o_pr   = 0;                                     // pairs int2
    size_t o_hsb  = al64(o_pr   + (size_t)e * 8);
    size_t o_h1   = al64(o_hsb  + (size_t)n * HID * 2);
    size_t o_agg1 = al64(o_h1   + (size_t)n * HID * 4);
    size_t o_dis  = al64(o_agg1 + (size_t)n * HID * 4);
    size_t o_gc   = al64(o_dis  + (size_t)n * 4);
    size_t o_go   = al64(o_gc   + (size_t)(MAXB + 2) * 4);
    size_t o_gu   = al64(o_go   + (size_t)(MAXB + 2) * 4);
    size_t o_wt   = al64(o_gu   + (size_t)(MAXB + 2) * 4);
    size_t need   = o_wt + 8192 * 2;
    bool sortedPath = (nbkt <= MAXB) && (ws_size >= need);

    if (sortedPath) {
        int2*           pairs   = (int2*)(wp + o_pr);
        unsigned short* hsb     = (unsigned short*)(wp + o_hsb);
        float*          h1      = (float*)(wp + o_h1);
        float*          agg1    = (float*)(wp + o_agg1);
        float*          dis     = (float*)(wp + o_dis);
        int*            gcount  = (int*)(wp + o_gc);
        int*            goff    = (int*)(wp + o_go);
        int*            gcursor = (int*)(wp + o_gu);
        unsigned short* Wt      = (unsigned short*)(wp + o_wt);

        size_t featBytes = (size_t)n * HID * sizeof(float);
        hipMemsetAsync(gcount, 0, (size_t)(MAXB + 2) * 4, stream);
        hipMemsetAsync(agg1, 0, featBytes, stream);
        hipMemsetAsync(outf, 0, featBytes, stream);

        khist<<<chBlk, 1024, 0, stream>>>(dsts, gcount, e, nbkt);
        kscan<<<1, 1024, 0, stream>>>(gcount, goff, gcursor, nbkt);
        kscatter<<<chBlk, 1024, 0, stream>>>(srcs, dsts, gcursor, pairs, e, nbkt);
        ksort<<<nbkt, 256, 0, stream>>>(pairs, goff, dis, n);

        prep_wt<<<32, 256, 0, stream>>>(W1, Wt);
        mm1_mfma<<<mmBlk, 256, 0, stream>>>(x, Wt, dis, h1, hsb, n);

        int waves = (e + 3) / 4;
        int psBlk = (waves + 3) / 4;
        prop_s<<<psBlk, 256, 0, stream>>>(pairs, hsb, agg1, e);
        mid<<<featBlk, 256, 0, stream>>>(agg1, h1, hsb, dis, b1, W2, n);
        prop_s<<<psBlk, 256, 0, stream>>>(pairs, hsb, outf, e);
        finalk<<<featBlk, 256, 0, stream>>>(outf, h1, dis, b2, eps, n);
    } else {
        // round-7 path (global fp32 atomics, 16 lanes/edge)
        char* fp = (char*)d_ws;
        size_t f_ideg = 0;
        size_t f_dis  = al64(f_ideg + (size_t)n * 4);
        size_t f_h1   = al64(f_dis  + (size_t)n * 4);
        size_t f_agg1 = al64(f_h1   + (size_t)n * HID * 4);
        size_t f_hsb  = al64(f_agg1 + (size_t)n * HID * 4);
        size_t f_wt   = al64(f_hsb  + (size_t)n * HID * 2);
        int*            ideg = (int*)(fp + f_ideg);
        float*          dis  = (float*)(fp + f_dis);
        float*          h1   = (float*)(fp + f_h1);
        float*          agg1 = (float*)(fp + f_agg1);
        unsigned short* hsb  = (unsigned short*)(fp + f_hsb);
        unsigned short* Wt   = (unsigned short*)(fp + f_wt);

        size_t featBytes = (size_t)n * HID * sizeof(float);
        hipMemsetAsync(ideg, 0, (size_t)n * sizeof(int), stream);
        hipMemsetAsync(agg1, 0, featBytes, stream);
        hipMemsetAsync(outf, 0, featBytes, stream);

        int eBlk    = (e + 255) / 256;
        int propBlk = (e * 16 + 255) / 256;
        prep_wt<<<32, 256, 0, stream>>>(W1, Wt);
        deg_count_int<<<eBlk, 256, 0, stream>>>(dsts, ideg, e);
        make_dis<<<nBlk, 256, 0, stream>>>(ideg, dis, n);
        mm1_mfma<<<mmBlk, 256, 0, stream>>>(x, Wt, dis, h1, hsb, n);
        prop<<<propBlk, 256, 0, stream>>>(srcs, dsts, hsb, agg1, e);
        mid<<<featBlk, 256, 0, stream>>>(agg1, h1, hsb, dis, b1, W2, n);
        prop<<<propBlk, 256, 0, stream>>>(srcs, dsts, hsb, outf, e);
        finalk<<<featBlk, 256, 0, stream>>>(outf, h1, dis, b2, eps, n);
    }
}

// Round 14
// 320.338 us; speedup vs baseline: 2.3916x; 1.3261x over previous
//
#include <hip/hip_runtime.h>
#include <hip/hip_bf16.h>

#define HID 16
#define NFEAT 512
#define BW 64           // nodes per bucket (dst >> 6)
#define CH 16384        // edges per histogram/scatter block
#define MAXB 2048       // max buckets supported by bucket path
#define SCAP 5120       // ksort LDS staging capacity (int2)

typedef __attribute__((ext_vector_type(8))) short bf16x8;
typedef __attribute__((ext_vector_type(4))) float f32x4;

__device__ __forceinline__ unsigned short f2b_hw(float f) {
    __hip_bfloat16 h = __float2bfloat16(f);
    return *reinterpret_cast<unsigned short*>(&h);
}
__device__ __forceinline__ float b2f(unsigned short b) {
    return __uint_as_float(((unsigned)b) << 16);
}

// ================= bucket build (proven round 8) =================
__global__ __launch_bounds__(1024) void khist(const int* __restrict__ dst,
                                              int* __restrict__ gcount, int e, int nbkt) {
    __shared__ int hist[MAXB];
    for (int t = threadIdx.x; t < nbkt; t += 1024) hist[t] = 0;
    __syncthreads();
    int base = blockIdx.x * CH;
#pragma unroll
    for (int k = 0; k < CH / 1024; ++k) {
        int i = base + k * 1024 + threadIdx.x;
        if (i < e) atomicAdd(&hist[dst[i] >> 6], 1);
    }
    __syncthreads();
    for (int t = threadIdx.x; t < nbkt; t += 1024)
        if (hist[t]) atomicAdd(&gcount[t], hist[t]);
}

__global__ __launch_bounds__(1024) void kscan(const int* __restrict__ gcount,
                                              int* __restrict__ goff,
                                              int* __restrict__ gcursor, int nbkt) {
    __shared__ int buf0[MAXB], buf1[MAXB];
    for (int t = threadIdx.x; t < MAXB; t += 1024) buf0[t] = (t < nbkt) ? gcount[t] : 0;
    __syncthreads();
    int* in = buf0; int* out = buf1;
    for (int d = 1; d < MAXB; d <<= 1) {
        for (int t = threadIdx.x; t < MAXB; t += 1024)
            out[t] = in[t] + (t >= d ? in[t - d] : 0);
        __syncthreads();
        int* tmp = in; in = out; out = tmp;
    }
    for (int t = threadIdx.x; t < nbkt; t += 1024) {
        int excl = in[t] - gcount[t];
        goff[t] = excl;
        gcursor[t] = excl;
    }
    if (threadIdx.x == 0) goff[nbkt] = in[nbkt - 1];
}

__global__ __launch_bounds__(1024) void kscatter(const int* __restrict__ src,
                                                 const int* __restrict__ dst,
                                                 int* __restrict__ gcursor,
                                                 int2* __restrict__ pairs, int e, int nbkt) {
    __shared__ int hist[MAXB];
    __shared__ int base[MAXB];
    for (int t = threadIdx.x; t < nbkt; t += 1024) hist[t] = 0;
    __syncthreads();
    int b0 = blockIdx.x * CH;
#pragma unroll
    for (int k = 0; k < CH / 1024; ++k) {
        int i = b0 + k * 1024 + threadIdx.x;
        if (i < e) atomicAdd(&hist[dst[i] >> 6], 1);
    }
    __syncthreads();
    for (int t = threadIdx.x; t < nbkt; t += 1024)
        base[t] = hist[t] ? atomicAdd(&gcursor[t], hist[t]) : 0;
    __syncthreads();
#pragma unroll
    for (int k = 0; k < CH / 1024; ++k) {
        int i = b0 + k * 1024 + threadIdx.x;
        if (i < e) {
            int d = dst[i];
            int pos = atomicAdd(&base[d >> 6], 1);   // LDS bump
            pairs[pos] = make_int2(src[i], d);
        }
    }
}

// ================= per-bucket counting sort by dst + dis (proven r13) =======
__global__ __launch_bounds__(256) void ksort(int2* __restrict__ pairs,
                                             const int* __restrict__ goff,
                                             float* __restrict__ dis, int n) {
    __shared__ int cnt[BW];
    __shared__ int ofs[BW];
    __shared__ int2 stg[SCAP];
    int b = blockIdx.x;
    int s0 = goff[b], s1 = goff[b + 1];
    int m = s1 - s0;
    if (threadIdx.x < BW) cnt[threadIdx.x] = 0;
    __syncthreads();
    bool fits = (m <= SCAP);
    if (fits) {
        for (int i = threadIdx.x; i < m; i += 256) {
            int2 p = pairs[s0 + i];
            stg[i] = p;
            atomicAdd(&cnt[p.y & (BW - 1)], 1);
        }
    } else {
        for (int i = threadIdx.x; i < m; i += 256)
            atomicAdd(&cnt[pairs[s0 + i].y & (BW - 1)], 1);
    }
    __syncthreads();
    if (threadIdx.x < BW) {
        int node = b * BW + threadIdx.x;
        if (node < n) dis[node] = rsqrtf(1.0f + (float)cnt[threadIdx.x]);
        int v = cnt[threadIdx.x];
        int inc = v;
        for (int d = 1; d < 64; d <<= 1) {
            int o = __shfl_up(inc, d);
            if (threadIdx.x >= (unsigned)d) inc += o;
        }
        ofs[threadIdx.x] = inc - v;
    }
    __syncthreads();
    if (fits) {
        for (int i = threadIdx.x; i < m; i += 256) {
            int2 p = stg[i];
            int pos = atomicAdd(&ofs[p.y & (BW - 1)], 1);
            pairs[s0 + pos] = p;
        }
    }
}

// ================= W1 -> Wt (bf16 transposed) =================
__global__ __launch_bounds__(256) void prep_wt(const float* __restrict__ W1,
                                               unsigned short* __restrict__ Wt) {
    int i = blockIdx.x * 256 + threadIdx.x;   // 8192 = 16*512
    int j = i >> 9, k = i & 511;
    Wt[i] = f2b_hw(W1[k * HID + j]);
}

// ================= h1 = x @ W1 via MFMA (proven round 7) =================
__global__ __launch_bounds__(256) void mm1_mfma(const float* __restrict__ x,
                                                const unsigned short* __restrict__ Wt,
                                                const float* __restrict__ dis,
                                                float* __restrict__ h1,
                                                unsigned short* __restrict__ hsb, int n) {
    int wid  = threadIdx.x >> 6;
    int lane = threadIdx.x & 63;
    int base = (blockIdx.x * 4 + wid) * 16;
    if (base >= n) return;
    int lrow = lane & 15;
    int kg   = lane >> 4;

    bf16x8 bfr[16];
#pragma unroll
    for (int t = 0; t < 16; ++t)
        bfr[t] = *(const bf16x8*)(Wt + lrow * NFEAT + t * 32 + kg * 8);

    int row = base + lrow;
    bool ok = (row < n);
    const float* xr = x + (size_t)(ok ? row : 0) * NFEAT;

    f32x4 acc = {0.f, 0.f, 0.f, 0.f};
#pragma unroll
    for (int t = 0; t < 16; ++t) {
        float4 u0 = *(const float4*)(xr + t * 32 + kg * 8);
        float4 u1 = *(const float4*)(xr + t * 32 + kg * 8 + 4);
        if (!ok) { u0 = make_float4(0,0,0,0); u1 = make_float4(0,0,0,0); }
        union { bf16x8 v; unsigned short u[8]; } A;
        A.u[0] = f2b_hw(u0.x); A.u[1] = f2b_hw(u0.y);
        A.u[2] = f2b_hw(u0.z); A.u[3] = f2b_hw(u0.w);
        A.u[4] = f2b_hw(u1.x); A.u[5] = f2b_hw(u1.y);
        A.u[6] = f2b_hw(u1.z); A.u[7] = f2b_hw(u1.w);
        acc = __builtin_amdgcn_mfma_f32_16x16x32_bf16(A.v, bfr[t], acc, 0, 0, 0);
    }

#pragma unroll
    for (int q = 0; q < 4; ++q) {
        int orow = base + kg * 4 + q;
        if (orow < n) {
            float v = acc[q];
            h1[(size_t)orow * HID + lrow] = v;
            hsb[(size_t)orow * HID + lrow] = f2b_hw(v * dis[orow]);
        }
    }
}

// ================= propagation: 16 edges/wave packed gather + run merge =====
// Round-13 prop_s spent its time on 800K gather-instructions/pass (16 lanes x
// 2B per edge). Here each lane gathers 8B (4 bf16) so ONE wave-instruction
// covers 16 edges -> 200K gather instrs/pass. Four shuffle sub-rounds
// redistribute to the (slot,j) layout, then the proven 4-slot suffix merge +
// leader atomic (unchanged RMW count ~850K).
__global__ __launch_bounds__(256) void prop_s16(const int2* __restrict__ pairs,
                                                const unsigned short* __restrict__ hsb,
                                                float* __restrict__ agg, int e) {
    int wave = blockIdx.x * 4 + (threadIdx.x >> 6);
    int lane = threadIdx.x & 63;
    int ebase = wave * 16;
    if (ebase >= e) return;

    int myE = ebase + (lane >> 2);
    int2 p = pairs[min(myE, e - 1)];
    uint2 g = *((const uint2*)(hsb + (size_t)p.x * HID) + (lane & 3));

    int slot = lane >> 4, j = lane & 15;
    int srcL0 = 4 * slot + (j >> 2);

#pragma unroll
    for (int r = 0; r < 4; ++r) {
        int sL = 16 * r + srcL0;
        int gx = __shfl((int)g.x, sL);
        int gy = __shfl((int)g.y, sL);
        int dd = __shfl(p.y, sL);
        int chosen = (j & 2) ? gy : gx;
        unsigned short hw = (j & 1) ? (unsigned short)(((unsigned)chosen) >> 16)
                                    : (unsigned short)(chosen & 0xffffu);
        int eidx = ebase + 4 * r + slot;
        bool valid = (eidx < e);
        int d = valid ? dd : -1;
        float val = valid ? b2f(hw) : 0.f;

        int   dn1 = __shfl_down(d, 16);
        float vn1 = __shfl_down(val, 16);
        if (slot < 3 && dn1 == d) val += vn1;
        int   dn2 = __shfl_down(d, 32);
        float vn2 = __shfl_down(val, 32);
        if (slot < 2 && dn2 == d) val += vn2;
        int dp = __shfl_up(d, 16);
        bool leader = (d >= 0) && (slot == 0 || dp != d);
        if (leader) atomicAdd(&agg[(size_t)d * HID + j], val);
    }
}

// ================= fused middle / final (proven) =================
__global__ __launch_bounds__(256) void mid(const float* __restrict__ agg1,
                                           float* __restrict__ h1,
                                           unsigned short* __restrict__ hsb,
                                           const float* __restrict__ dis,
                                           const float* __restrict__ b1,
                                           const float* __restrict__ W2, int n) {
    __shared__ float W2s[HID * HID];
    W2s[threadIdx.x] = W2[threadIdx.x];
    __syncthreads();
    int idx = blockIdx.x * 256 + threadIdx.x;
    int v = idx >> 4, j = idx & 15;
    if (v >= n) return;
    float dn = dis[v];
    float a = dn * agg1[idx] + dn * dn * h1[idx] + b1[j];
    float hv = fmaxf(a, 0.f);
    float h2 = 0.f;
#pragma unroll
    for (int k = 0; k < HID; ++k)
        h2 += __shfl(hv, k, HID) * W2s[k * HID + j];
    h1[idx] = h2;
    hsb[idx] = f2b_hw(h2 * dn);
}

__global__ __launch_bounds__(256) void finalk(float* __restrict__ out,
                                              const float* __restrict__ h2,
                                              const float* __restrict__ dis,
                                              const float* __restrict__ b2,
                                              const float* __restrict__ eps, int n) {
    int idx = blockIdx.x * 256 + threadIdx.x;
    int v = idx >> 4, j = idx & 15;
    if (v >= n) return;
    float dn = dis[v];
    float z = dn * out[idx] + dn * dn * h2[idx] + b2[j];
    out[idx] = z + eps[idx] * expf(0.5f * z);
}

// ================= fallback (round-7 atomic path) =================
__global__ __launch_bounds__(256) void deg_count_int(const int* __restrict__ dst,
                                                     int* __restrict__ ideg, int e) {
    int i = blockIdx.x * 256 + threadIdx.x;
    if (i < e) atomicAdd(&ideg[dst[i]], 1);
}
__global__ __launch_bounds__(256) void make_dis(const int* __restrict__ ideg,
                                                float* __restrict__ dis, int n) {
    int i = blockIdx.x * 256 + threadIdx.x;
    if (i < n) dis[i] = rsqrtf(1.0f + (float)ideg[i]);
}
__global__ __launch_bounds__(256) void prop(const int* __restrict__ src,
                                            const int* __restrict__ dst,
                                            const unsigned short* __restrict__ hsb,
                                            float* __restrict__ agg, int e) {
    int idx = blockIdx.x * 256 + threadIdx.x;
    int ed = idx >> 4, j = idx & 15;
    if (ed >= e) return;
    int s = src[ed], d = dst[ed];
    atomicAdd(&agg[(size_t)d * HID + j], b2f(hsb[(size_t)s * HID + j]));
}

static inline size_t al64(size_t x) { return (x + 63) & ~(size_t)63; }

extern "C" void kernel_launch(void* const* d_in, const int* in_sizes, int n_in,
                              void* d_out, int out_size, void* d_ws, size_t ws_size,
                              hipStream_t stream) {
    const float* x   = (const float*)d_in[0];
    const float* W1  = (const float*)d_in[1];
    const float* b1  = (const float*)d_in[2];
    const float* W2  = (const float*)d_in[3];
    const float* b2  = (const float*)d_in[4];
    const float* eps = (const float*)d_in[5];
    const int*   ei  = (const int*)d_in[6];

    int n = in_sizes[5] / HID;   // 100000
    int e = in_sizes[6] / 2;     // 3200000
    const int* srcs = ei;
    const int* dsts = ei + e;
    float* outf = (float*)d_out;

    int nbkt    = (n + BW - 1) / BW;         // 1563
    int nBlk    = (n + 255) / 256;
    int mmBlk   = (n + 63) / 64;
    int featBlk = (n * 16 + 255) / 256;
    int chBlk   = (e + CH - 1) / CH;         // 196

    // ws layout, 64B-aligned regions
    char* wp = (char*)d_ws;
    size_t o_pr   = 0;                                     // pairs int2
    size_t o_hsb  = al64(o_pr   + (size_t)e * 8);
    size_t o_h1   = al64(o_hsb  + (size_t)n * HID * 2);
    size_t o_agg1 = al64(o_h1   + (size_t)n * HID * 4);
    size_t o_dis  = al64(o_agg1 + (size_t)n * HID * 4);
    size_t o_gc   = al64(o_dis  + (size_t)n * 4);
    size_t o_go   = al64(o_gc   + (size_t)(MAXB + 2) * 4);
    size_t o_gu   = al64(o_go   + (size_t)(MAXB + 2) * 4);
    size_t o_wt   = al64(o_gu   + (size_t)(MAXB + 2) * 4);
    size_t need   = o_wt + 8192 * 2;
    bool sortedPath = (nbkt <= MAXB) && (ws_size >= need);

    if (sortedPath) {
        int2*           pairs   = (int2*)(wp + o_pr);
        unsigned short* hsb     = (unsigned short*)(wp + o_hsb);
        float*          h1      = (float*)(wp + o_h1);
        float*          agg1    = (float*)(wp + o_agg1);
        float*          dis     = (float*)(wp + o_dis);
        int*            gcount  = (int*)(wp + o_gc);
        int*            goff    = (int*)(wp + o_go);
        int*            gcursor = (int*)(wp + o_gu);
        unsigned short* Wt      = (unsigned short*)(wp + o_wt);

        size_t featBytes = (size_t)n * HID * sizeof(float);
        hipMemsetAsync(gcount, 0, (size_t)(MAXB + 2) * 4, stream);
        hipMemsetAsync(agg1, 0, featBytes, stream);
        hipMemsetAsync(outf, 0, featBytes, stream);

        khist<<<chBlk, 1024, 0, stream>>>(dsts, gcount, e, nbkt);
        kscan<<<1, 1024, 0, stream>>>(gcount, goff, gcursor, nbkt);
        kscatter<<<chBlk, 1024, 0, stream>>>(srcs, dsts, gcursor, pairs, e, nbkt);
        ksort<<<nbkt, 256, 0, stream>>>(pairs, goff, dis, n);

        prep_wt<<<32, 256, 0, stream>>>(W1, Wt);
        mm1_mfma<<<mmBlk, 256, 0, stream>>>(x, Wt, dis, h1, hsb, n);

        int waves = (e + 15) / 16;
        int psBlk = (waves + 3) / 4;
        prop_s16<<<psBlk, 256, 0, stream>>>(pairs, hsb, agg1, e);
        mid<<<featBlk, 256, 0, stream>>>(agg1, h1, hsb, dis, b1, W2, n);
        prop_s16<<<psBlk, 256, 0, stream>>>(pairs, hsb, outf, e);
        finalk<<<featBlk, 256, 0, stream>>>(outf, h1, dis, b2, eps, n);
    } else {
        // round-7 path (global fp32 atomics, 16 lanes/edge)
        char* fp = (char*)d_ws;
        size_t f_ideg = 0;
        size_t f_dis  = al64(f_ideg + (size_t)n * 4);
        size_t f_h1   = al64(f_dis  + (size_t)n * 4);
        size_t f_agg1 = al64(f_h1   + (size_t)n * HID * 4);
        size_t f_hsb  = al64(f_agg1 + (size_t)n * HID * 4);
        size_t f_wt   = al64(f_hsb  + (size_t)n * HID * 2);
        int*            ideg = (int*)(fp + f_ideg);
        float*          dis  = (float*)(fp + f_dis);
        float*          h1   = (float*)(fp + f_h1);
        float*          agg1 = (float*)(fp + f_agg1);
        unsigned short* hsb  = (unsigned short*)(fp + f_hsb);
        unsigned short* Wt   = (unsigned short*)(fp + f_wt);

        size_t featBytes = (size_t)n * HID * sizeof(float);
        hipMemsetAsync(ideg, 0, (size_t)n * sizeof(int), stream);
        hipMemsetAsync(agg1, 0, featBytes, stream);
        hipMemsetAsync(outf, 0, featBytes, stream);

        int eBlk    = (e + 255) / 256;
        int propBlk = (e * 16 + 255) / 256;
        prep_wt<<<32, 256, 0, stream>>>(W1, Wt);
        deg_count_int<<<eBlk, 256, 0, stream>>>(dsts, ideg, e);
        make_dis<<<nBlk, 256, 0, stream>>>(ideg, dis, n);
        mm1_mfma<<<mmBlk, 256, 0, stream>>>(x, Wt, dis, h1, hsb, n);
        prop<<<propBlk, 256, 0, stream>>>(srcs, dsts, hsb, agg1, e);
        mid<<<featBlk, 256, 0, stream>>>(agg1, h1, hsb, dis, b1, W2, n);
        prop<<<propBlk, 256, 0, stream>>>(srcs, dsts, hsb, outf, e);
        finalk<<<featBlk, 256, 0, stream>>>(outf, h1, dis, b2, eps, n);
    }
}